// Round 7
// baseline (570.288 us; speedup 1.0000x reference)
//
#include <hip/hip_runtime.h>
#include <hip/hip_cooperative_groups.h>

namespace cg = cooperative_groups;

#define NROW 8192
#define DIN  512
#define DOUT 256
#define NCHUNK 256
#define CLEN 32   // NCHUNK*CLEN == NROW

// ---------------- workspace layout (bytes) ----------------
constexpr size_t OFF_H      = 0;                              // 8192*256*4
constexpr size_t OFF_S1     = OFF_H + (size_t)NROW*DOUT*4;    // ---- memset region start
constexpr size_t OFF_S2     = OFF_S1 + NROW*4;
constexpr size_t OFF_RANK   = OFF_S2 + NROW*4;
constexpr size_t OFF_MISC   = OFF_RANK + NROW*4;              // [0]=enc-max u32, [1]=M1 float
constexpr size_t MEMSET_LEN = OFF_MISC + 256 - OFF_S1;        // s1,s2,rank,misc contiguous
constexpr size_t OFF_S1S    = OFF_MISC + 256;
constexpr size_t OFF_PERM   = OFF_S1S + NROW*4;
constexpr size_t OFF_WHI    = OFF_PERM + NROW*4;
constexpr size_t OFF_WLO    = OFF_WHI + NROW*4;
constexpr size_t OFF_PRELOS = OFF_WLO + NROW*4;               // 8193 floats, padded
constexpr size_t OFF_SUFHIS = OFF_PRELOS + 33024;
constexpr size_t OFF_CSLO   = OFF_SUFHIS + 33024;             // [NCHUNK] scalar chunk sums
constexpr size_t OFF_CSHI   = OFF_CSLO + 1024;
constexpr size_t OFF_TLO    = OFF_CSHI + 1024;                // [NCHUNK][256]
constexpr size_t OFF_THI    = OFF_TLO + (size_t)NCHUNK*DOUT*4;
constexpr size_t OFF_PRELO  = OFF_THI + (size_t)NCHUNK*DOUT*4;  // [8193][256]
constexpr size_t OFF_SUFHI  = OFF_PRELO + (size_t)(NROW+1)*DOUT*4;
constexpr size_t WS_NEED    = OFF_SUFHI + (size_t)(NROW+1)*DOUT*4;

typedef float f32x4 __attribute__((ext_vector_type(4)));
typedef short s16x8 __attribute__((ext_vector_type(8)));
typedef unsigned int u32x4 __attribute__((ext_vector_type(4)));

// fp32 x8 -> bf16 hi/lo TRUNCATING split, 3 VALU ops/element (v_perm packs
// two truncations per instruction). Error on h ~2e-5, two orders below the
// observed absmax floor.
__device__ __forceinline__ void cvt8_pair(const float4 u, const float4 v,
                                          s16x8& hi, s16x8& lo) {
  float f[8] = {u.x, u.y, u.z, u.w, v.x, v.y, v.z, v.w};
  u32x4 hp, lp;
#pragma unroll
  for (int p = 0; p < 4; ++p) {
    const float f0 = f[2 * p], f1 = f[2 * p + 1];
    const unsigned b0 = __float_as_uint(f0);
    const unsigned b1 = __float_as_uint(f1);
    hp[p] = __builtin_amdgcn_perm(b1, b0, 0x07060302u);  // [f0.hi16, f1.hi16]
    const float r0 = f0 - __uint_as_float(b0 & 0xffff0000u);
    const float r1 = f1 - __uint_as_float(b1 & 0xffff0000u);
    lp[p] = __builtin_amdgcn_perm(__float_as_uint(r1), __float_as_uint(r0), 0x07060302u);
  }
  hi = __builtin_bit_cast(s16x8, hp);
  lo = __builtin_bit_cast(s16x8, lp);
}

// ------- kernel 1: h = x @ W^T via split-bf16 MFMA, fused s1/s2 ------------
// (unchanged from round 6: 64x64 tile, BK=64, 512 blocks = 2/CU, XCD swizzle,
//  in-kernel truncating fp32->bf16 hi/lo conversion)
__global__ __launch_bounds__(256) void gemm_h_mfma(const float* __restrict__ x,
                                                   const float* __restrict__ W,
                                                   const float* __restrict__ a1,
                                                   const float* __restrict__ a2,
                                                   float* __restrict__ h,
                                                   float* __restrict__ s1,
                                                   float* __restrict__ s2) {
  __shared__ unsigned short AsH[64][72], AsL[64][72], BsH[64][72], BsL[64][72];
  const int tid = threadIdx.x;
  const int bid = blockIdx.x;
  const int swz = (bid & 7) * 64 + (bid >> 3);
  const int rowBase = (swz >> 2) * 64;
  const int colBase = (swz & 3) * 64;
  const int wid = tid >> 6, lane = tid & 63;
  const int wRow = wid >> 1, wCol = wid & 1;
  const int lhi = lane >> 4, llo = lane & 15;

  f32x4 acc[2][2];
#pragma unroll
  for (int m = 0; m < 2; ++m)
#pragma unroll
    for (int n = 0; n < 2; ++n) acc[m][n] = (f32x4)(0.f);

  const int tr = tid >> 2;
  const int tq = tid & 3;
  const float* px = x + (size_t)(rowBase + tr) * DIN + tq * 16;
  const float* pw = W + (size_t)(colBase + tr) * DIN + tq * 16;

  s16x8 cAh[2], cAl[2], cBh[2], cBl[2];
  {
    float4 a0 = *(const float4*)(px + 0),  a1v = *(const float4*)(px + 4);
    float4 a2v = *(const float4*)(px + 8), a3 = *(const float4*)(px + 12);
    float4 b0 = *(const float4*)(pw + 0),  b1 = *(const float4*)(pw + 4);
    float4 b2 = *(const float4*)(pw + 8),  b3 = *(const float4*)(pw + 12);
    cvt8_pair(a0, a1v, cAh[0], cAl[0]);
    cvt8_pair(a2v, a3, cAh[1], cAl[1]);
    cvt8_pair(b0, b1, cBh[0], cBl[0]);
    cvt8_pair(b2, b3, cBh[1], cBl[1]);
  }

  for (int k0 = 0; k0 < DIN; k0 += 64) {
    __syncthreads();
    *(s16x8*)&AsH[tr][tq * 16 + 0] = cAh[0];
    *(s16x8*)&AsH[tr][tq * 16 + 8] = cAh[1];
    *(s16x8*)&AsL[tr][tq * 16 + 0] = cAl[0];
    *(s16x8*)&AsL[tr][tq * 16 + 8] = cAl[1];
    *(s16x8*)&BsH[tr][tq * 16 + 0] = cBh[0];
    *(s16x8*)&BsH[tr][tq * 16 + 8] = cBh[1];
    *(s16x8*)&BsL[tr][tq * 16 + 0] = cBl[0];
    *(s16x8*)&BsL[tr][tq * 16 + 8] = cBl[1];
    __syncthreads();
    const bool more = (k0 + 64 < DIN);
    float4 a0, a1v, a2v, a3, b0, b1, b2, b3;
    if (more) {
      a0 = *(const float4*)(px + k0 + 64 + 0);  a1v = *(const float4*)(px + k0 + 64 + 4);
      a2v = *(const float4*)(px + k0 + 64 + 8); a3 = *(const float4*)(px + k0 + 64 + 12);
      b0 = *(const float4*)(pw + k0 + 64 + 0);  b1 = *(const float4*)(pw + k0 + 64 + 4);
      b2 = *(const float4*)(pw + k0 + 64 + 8);  b3 = *(const float4*)(pw + k0 + 64 + 12);
    }
#pragma unroll
    for (int kk = 0; kk < 64; kk += 32) {
      s16x8 afh[2], afl[2], bfh[2], bfl[2];
#pragma unroll
      for (int m = 0; m < 2; ++m) {
        afh[m] = *(const s16x8*)&AsH[wRow * 32 + m * 16 + llo][kk + lhi * 8];
        afl[m] = *(const s16x8*)&AsL[wRow * 32 + m * 16 + llo][kk + lhi * 8];
      }
#pragma unroll
      for (int n = 0; n < 2; ++n) {
        bfh[n] = *(const s16x8*)&BsH[wCol * 32 + n * 16 + llo][kk + lhi * 8];
        bfl[n] = *(const s16x8*)&BsL[wCol * 32 + n * 16 + llo][kk + lhi * 8];
      }
#pragma unroll
      for (int m = 0; m < 2; ++m)
#pragma unroll
        for (int n = 0; n < 2; ++n) {
          acc[m][n] = __builtin_amdgcn_mfma_f32_16x16x32_bf16(afh[m], bfh[n], acc[m][n], 0, 0, 0);
          acc[m][n] = __builtin_amdgcn_mfma_f32_16x16x32_bf16(afl[m], bfh[n], acc[m][n], 0, 0, 0);
          acc[m][n] = __builtin_amdgcn_mfma_f32_16x16x32_bf16(afh[m], bfl[n], acc[m][n], 0, 0, 0);
        }
    }
    if (more) {
      cvt8_pair(a0, a1v, cAh[0], cAl[0]);
      cvt8_pair(a2v, a3, cAh[1], cAl[1]);
      cvt8_pair(b0, b1, cBh[0], cBl[0]);
      cvt8_pair(b2, b3, cBh[1], cBl[1]);
    }
  }
  float a1c[2], a2c[2];
#pragma unroll
  for (int n = 0; n < 2; ++n) {
    const int col = colBase + wCol * 32 + n * 16 + llo;
    a1c[n] = a1[col];
    a2c[n] = a2[col];
  }
#pragma unroll
  for (int m = 0; m < 2; ++m) {
    float p1[4] = {0.f, 0.f, 0.f, 0.f}, p2[4] = {0.f, 0.f, 0.f, 0.f};
#pragma unroll
    for (int n = 0; n < 2; ++n) {
      const int col = colBase + wCol * 32 + n * 16 + llo;
#pragma unroll
      for (int j = 0; j < 4; ++j) {
        const int row = rowBase + wRow * 32 + m * 16 + lhi * 4 + j;
        h[(size_t)row * DOUT + col] = acc[m][n][j];
        p1[j] = fmaf(acc[m][n][j], a1c[n], p1[j]);
        p2[j] = fmaf(acc[m][n][j], a2c[n], p2[j]);
      }
    }
#pragma unroll
    for (int j = 0; j < 4; ++j) {
#pragma unroll
      for (int msk = 1; msk < 16; msk <<= 1) {
        p1[j] += __shfl_xor(p1[j], msk);
        p2[j] += __shfl_xor(p2[j], msk);
      }
    }
    if (llo == 0) {
#pragma unroll
      for (int j = 0; j < 4; ++j) {
        const int row = rowBase + wRow * 32 + m * 16 + lhi * 4 + j;
        atomicAdd(&s1[row], p1[j]);
        atomicAdd(&s2[row], p2[j]);
      }
    }
  }
}

// ------- fused cooperative back-end: rank -> scatter -> chunk -> prefix ----
// -> finalize, with grid.sync() between phases. 512 blocks x 256 thr, ~2 KB
// LDS, low VGPR -> trivially co-resident. Phase bodies identical to the
// standalone kernels (rank j-window 512 instead of 1024 — partition only).
__global__ __launch_bounds__(256) void backend(const float* __restrict__ s1,
                                               const float* __restrict__ s2,
                                               int* __restrict__ rank,
                                               unsigned int* __restrict__ miscu,
                                               float* __restrict__ miscf,
                                               float* __restrict__ s1s,
                                               int* __restrict__ perm,
                                               float* __restrict__ w_hi,
                                               float* __restrict__ w_lo,
                                               const float* __restrict__ h,
                                               float* __restrict__ T_lo,
                                               float* __restrict__ T_hi,
                                               float* __restrict__ cs_lo,
                                               float* __restrict__ cs_hi,
                                               float* __restrict__ PreLo,
                                               float* __restrict__ SufHi,
                                               float* __restrict__ prelo_s,
                                               float* __restrict__ sufhi_s,
                                               float* __restrict__ out) {
  cg::grid_group grid = cg::this_grid();
  __shared__ float sjA[512];
  __shared__ float wm[4];
  const int t = threadIdx.x;
  const int b = blockIdx.x;

  // ---- phase A: rank counting + global max (512 blocks: 32 ib x 16 jc) ----
  {
    const int ib = b >> 4, jc = b & 15;
    const int j0 = jc * 512;
    if (t < 128) *(float4*)&sjA[t << 2] = *(const float4*)(s1 + j0 + (t << 2));
    const int i = ib * 256 + t;
    const float v = s1[i];
    __syncthreads();
    int cnt = 0;
#pragma unroll 4
    for (int q = 0; q < 128; ++q) {
      float4 sv = *(const float4*)&sjA[q << 2];
      int jg = j0 + (q << 2);
      cnt += (int)(sv.x < v) + (int)((sv.x == v) & (jg + 0 < i));
      cnt += (int)(sv.y < v) + (int)((sv.y == v) & (jg + 1 < i));
      cnt += (int)(sv.z < v) + (int)((sv.z == v) & (jg + 2 < i));
      cnt += (int)(sv.w < v) + (int)((sv.w == v) & (jg + 3 < i));
    }
    atomicAdd(&rank[i], cnt);
    if (jc == 0) {
      float m = v;
#pragma unroll
      for (int off = 32; off > 0; off >>= 1) m = fmaxf(m, __shfl_down(m, off));
      if ((t & 63) == 0) wm[t >> 6] = m;
      __syncthreads();
      if (t == 0) {
        float mm = fmaxf(fmaxf(wm[0], wm[1]), fmaxf(wm[2], wm[3]));
        unsigned int bb = __float_as_uint(mm);
        unsigned int enc = (bb & 0x80000000u) ? ~bb : (bb | 0x80000000u);
        atomicMax(miscu, enc);
      }
    }
  }
  grid.sync();

  // ---- phase B: scatter + exp weights (blocks 0..31) ----------------------
  if (b < 32) {
    const int i = b * 256 + t;
    unsigned int e = miscu[0];
    unsigned int bb = (e & 0x80000000u) ? (e & 0x7fffffffu) : ~e;
    const float M1 = __uint_as_float(bb);
    const float v = s1[i];
    const int r = rank[i];
    s1s[r] = v;
    perm[r] = i;
    w_hi[r] = __expf(v - M1);
    w_lo[r] = __expf(0.2f * (v - M1));
    if (i == 0) miscf[0] = M1;
  }
  grid.sync();

  // ---- phase C: per-chunk weighted totals (blocks 0..255) -----------------
  if (b < NCHUNK) {
    const int d = t;
    const int j0 = b * CLEN;
    float tlo = 0.f, thi = 0.f;
#pragma unroll
    for (int e = 0; e < CLEN; e += 4) {
      int4 p4 = *(const int4*)(perm + j0 + e);
      float4 wl4 = *(const float4*)(w_lo + j0 + e);
      float4 wh4 = *(const float4*)(w_hi + j0 + e);
      float h0 = h[(size_t)p4.x * DOUT + d];
      float h1 = h[(size_t)p4.y * DOUT + d];
      float h2 = h[(size_t)p4.z * DOUT + d];
      float h3 = h[(size_t)p4.w * DOUT + d];
      tlo += wl4.x * h0 + wl4.y * h1 + wl4.z * h2 + wl4.w * h3;
      thi += wh4.x * h0 + wh4.y * h1 + wh4.z * h2 + wh4.w * h3;
    }
    T_lo[b * DOUT + d] = tlo;
    T_hi[b * DOUT + d] = thi;
    if (d < 64) {
      float wl = (d < 32) ? w_lo[j0 + d] : 0.f;
      float wh = (d < 32) ? w_hi[j0 + d] : 0.f;
#pragma unroll
      for (int off = 32; off > 0; off >>= 1) {
        wl += __shfl_down(wl, off);
        wh += __shfl_down(wh, off);
      }
      if (d == 0) { cs_lo[b] = wl; cs_hi[b] = wh; }
    }
  }
  grid.sync();

  // ---- phase D: chunk-offset sums + PreLo/SufHi materialize ---------------
  if (b < NCHUNK) {
    const int d = t;
    const int j0 = b * CLEN;
    if (d < 64) {
      float accp = 0.f, acct = 0.f;
      for (int p = d; p < NCHUNK; p += 64) {
        float cl = cs_lo[p], ch = cs_hi[p];
        accp += (p < b) ? cl : 0.f;
        acct += (p > b) ? ch : 0.f;
      }
#pragma unroll
      for (int off = 32; off > 0; off >>= 1) {
        accp += __shfl_down(accp, off);
        acct += __shfl_down(acct, off);
      }
      float pres  = __shfl(accp, 0);
      float tails = __shfl(acct, 0);
      float wl = (d < 32) ? w_lo[j0 + d] : 0.f;
      float wh = (d < 32) ? w_hi[j0 + d] : 0.f;
      float pl = wl, ph = wh;
#pragma unroll
      for (int off = 1; off < 32; off <<= 1) {
        float a = __shfl_up(pl, off);
        float c = __shfl_up(ph, off);
        if (d >= off) { pl += a; ph += c; }
      }
      float chunk_hi_tot = __shfl(ph, 31);
      if (d < 32) {
        prelo_s[j0 + d] = pres + (pl - wl);
        sufhi_s[j0 + d] = tails + (chunk_hi_tot - (ph - wh));
      }
      if (b == NCHUNK - 1 && d == 31) {
        prelo_s[NROW] = pres + pl;
        sufhi_s[NROW] = 0.f;
      }
    }
    float rl = 0.f, tail = 0.f;
#pragma unroll 4
    for (int p = 0; p < b; ++p)           rl   += T_lo[p * DOUT + d];
#pragma unroll 4
    for (int p = b + 1; p < NCHUNK; ++p)  tail += T_hi[p * DOUT + d];
    float phl[CLEN], phh[CLEN];
    float ownHi = 0.f;
#pragma unroll
    for (int e = 0; e < CLEN; e += 4) {
      int4 p4 = *(const int4*)(perm + j0 + e);
      float4 wl4 = *(const float4*)(w_lo + j0 + e);
      float4 wh4 = *(const float4*)(w_hi + j0 + e);
      float h0 = h[(size_t)p4.x * DOUT + d];
      float h1 = h[(size_t)p4.y * DOUT + d];
      float h2 = h[(size_t)p4.z * DOUT + d];
      float h3 = h[(size_t)p4.w * DOUT + d];
      phl[e + 0] = wl4.x * h0; phl[e + 1] = wl4.y * h1;
      phl[e + 2] = wl4.z * h2; phl[e + 3] = wl4.w * h3;
      phh[e + 0] = wh4.x * h0; phh[e + 1] = wh4.y * h1;
      phh[e + 2] = wh4.z * h2; phh[e + 3] = wh4.w * h3;
      ownHi += phh[e + 0] + phh[e + 1] + phh[e + 2] + phh[e + 3];
    }
    float shb = tail + ownHi;
    float preh = 0.f;
#pragma unroll
    for (int e = 0; e < CLEN; ++e) {
      size_t j = (size_t)(j0 + e);
      PreLo[j * DOUT + d] = rl;
      SufHi[j * DOUT + d] = shb - preh;
      rl   += phl[e];
      preh += phh[e];
    }
    if (b == NCHUNK - 1) {
      PreLo[(size_t)NROW * DOUT + d] = rl;
      SufHi[(size_t)NROW * DOUT + d] = 0.f;
    }
  }
  grid.sync();

  // ---- phase E: per-row combine (all 512 blocks, 4 rows/wave) -------------
  {
    const int wave = t >> 6, lane = t & 63;
    const float M1 = miscf[0];
#pragma unroll
    for (int rep = 0; rep < 4; ++rep) {
      const int i = b * 16 + wave * 4 + rep;
      const float c = s2[i];
      const float tval = -c;
      int lo = 0, hi = NROW;
      while (lo < hi) {
        int mid = (lo + hi) >> 1;
        if (s1s[mid] <= tval) lo = mid + 1; else hi = mid;
      }
      const int k = lo;
      const float u = c + M1;
      const float m = fmaxf(u, 0.2f * u);
      const float fh = __expf(u - m);
      const float fl = __expf(0.2f * u - m);
      const float den = fh * sufhi_s[k] + fl * prelo_s[k];
      const float inv = 1.f / den;
      float4 A = *(const float4*)(SufHi + (size_t)k * DOUT + (lane << 2));
      float4 B = *(const float4*)(PreLo + (size_t)k * DOUT + (lane << 2));
      float4 o;
      o.x = (fh * A.x + fl * B.x) * inv;
      o.y = (fh * A.y + fl * B.y) * inv;
      o.z = (fh * A.z + fl * B.z) * inv;
      o.w = (fh * A.w + fl * B.w) * inv;
      *(float4*)(out + (size_t)i * DOUT + (lane << 2)) = o;
    }
  }
}

// ---------------- fallback standalone kernels (used if coop launch fails) --
__global__ __launch_bounds__(256) void rank_count(const float* __restrict__ s1,
                                                  int* __restrict__ rank,
                                                  unsigned int* __restrict__ miscu) {
  __shared__ float sj[1024];
  __shared__ float wm[4];
  const int t = threadIdx.x;
  const int ib = blockIdx.x, jc = blockIdx.y;
  const int j0 = jc * 1024;
  *(float4*)&sj[t << 2] = *(const float4*)(s1 + j0 + (t << 2));
  const int i = ib * 256 + t;
  const float v = s1[i];
  __syncthreads();
  int cnt = 0;
#pragma unroll 4
  for (int q = 0; q < 256; ++q) {
    float4 sv = *(const float4*)&sj[q << 2];
    int jg = j0 + (q << 2);
    cnt += (int)(sv.x < v) + (int)((sv.x == v) & (jg + 0 < i));
    cnt += (int)(sv.y < v) + (int)((sv.y == v) & (jg + 1 < i));
    cnt += (int)(sv.z < v) + (int)((sv.z == v) & (jg + 2 < i));
    cnt += (int)(sv.w < v) + (int)((sv.w == v) & (jg + 3 < i));
  }
  atomicAdd(&rank[i], cnt);
  if (jc == 0) {
    float m = v;
#pragma unroll
    for (int off = 32; off > 0; off >>= 1) m = fmaxf(m, __shfl_down(m, off));
    if ((t & 63) == 0) wm[t >> 6] = m;
    __syncthreads();
    if (t == 0) {
      float mm = fmaxf(fmaxf(wm[0], wm[1]), fmaxf(wm[2], wm[3]));
      unsigned int b = __float_as_uint(mm);
      unsigned int enc = (b & 0x80000000u) ? ~b : (b | 0x80000000u);
      atomicMax(miscu, enc);
    }
  }
}

__global__ __launch_bounds__(256) void scatter_w(const float* __restrict__ s1,
                                                 const int* __restrict__ rank,
                                                 const unsigned int* __restrict__ miscu,
                                                 float* __restrict__ miscf,
                                                 float* __restrict__ s1s,
                                                 int* __restrict__ perm,
                                                 float* __restrict__ w_hi,
                                                 float* __restrict__ w_lo) {
  const int i = blockIdx.x * 256 + threadIdx.x;
  unsigned int e = miscu[0];
  unsigned int b = (e & 0x80000000u) ? (e & 0x7fffffffu) : ~e;
  const float M1 = __uint_as_float(b);
  const float v = s1[i];
  const int r = rank[i];
  s1s[r] = v;
  perm[r] = i;
  w_hi[r] = __expf(v - M1);
  w_lo[r] = __expf(0.2f * (v - M1));
  if (i == 0) miscf[0] = M1;
}

__global__ __launch_bounds__(256) void chunk_totals(const float* __restrict__ h,
                                                    const int* __restrict__ perm,
                                                    const float* __restrict__ w_hi,
                                                    const float* __restrict__ w_lo,
                                                    float* __restrict__ T_lo,
                                                    float* __restrict__ T_hi,
                                                    float* __restrict__ cs_lo,
                                                    float* __restrict__ cs_hi) {
  const int d = threadIdx.x, b = blockIdx.x;
  const int j0 = b * CLEN;
  float tlo = 0.f, thi = 0.f;
#pragma unroll
  for (int e = 0; e < CLEN; e += 4) {
    int4 p4 = *(const int4*)(perm + j0 + e);
    float4 wl4 = *(const float4*)(w_lo + j0 + e);
    float4 wh4 = *(const float4*)(w_hi + j0 + e);
    float h0 = h[(size_t)p4.x * DOUT + d];
    float h1 = h[(size_t)p4.y * DOUT + d];
    float h2 = h[(size_t)p4.z * DOUT + d];
    float h3 = h[(size_t)p4.w * DOUT + d];
    tlo += wl4.x * h0 + wl4.y * h1 + wl4.z * h2 + wl4.w * h3;
    thi += wh4.x * h0 + wh4.y * h1 + wh4.z * h2 + wh4.w * h3;
  }
  T_lo[b * DOUT + d] = tlo;
  T_hi[b * DOUT + d] = thi;
  if (d < 64) {
    float wl = (d < 32) ? w_lo[j0 + d] : 0.f;
    float wh = (d < 32) ? w_hi[j0 + d] : 0.f;
#pragma unroll
    for (int off = 32; off > 0; off >>= 1) {
      wl += __shfl_down(wl, off);
      wh += __shfl_down(wh, off);
    }
    if (d == 0) { cs_lo[b] = wl; cs_hi[b] = wh; }
  }
}

__global__ __launch_bounds__(256) void write_prefix(const float* __restrict__ h,
                                                    const int* __restrict__ perm,
                                                    const float* __restrict__ w_hi,
                                                    const float* __restrict__ w_lo,
                                                    const float* __restrict__ T_lo,
                                                    const float* __restrict__ T_hi,
                                                    const float* __restrict__ cs_lo,
                                                    const float* __restrict__ cs_hi,
                                                    float* __restrict__ PreLo,
                                                    float* __restrict__ SufHi,
                                                    float* __restrict__ prelo_s,
                                                    float* __restrict__ sufhi_s) {
  const int d = threadIdx.x, b = blockIdx.x;
  const int j0 = b * CLEN;
  if (d < 64) {
    float accp = 0.f, acct = 0.f;
    for (int p = d; p < NCHUNK; p += 64) {
      float cl = cs_lo[p], ch = cs_hi[p];
      accp += (p < b) ? cl : 0.f;
      acct += (p > b) ? ch : 0.f;
    }
#pragma unroll
    for (int off = 32; off > 0; off >>= 1) {
      accp += __shfl_down(accp, off);
      acct += __shfl_down(acct, off);
    }
    float pres  = __shfl(accp, 0);
    float tails = __shfl(acct, 0);
    float wl = (d < 32) ? w_lo[j0 + d] : 0.f;
    float wh = (d < 32) ? w_hi[j0 + d] : 0.f;
    float pl = wl, ph = wh;
#pragma unroll
    for (int off = 1; off < 32; off <<= 1) {
      float a = __shfl_up(pl, off);
      float c = __shfl_up(ph, off);
      if (d >= off) { pl += a; ph += c; }
    }
    float chunk_hi_tot = __shfl(ph, 31);
    if (d < 32) {
      prelo_s[j0 + d] = pres + (pl - wl);
      sufhi_s[j0 + d] = tails + (chunk_hi_tot - (ph - wh));
    }
    if (b == NCHUNK - 1 && d == 31) {
      prelo_s[NROW] = pres + pl;
      sufhi_s[NROW] = 0.f;
    }
  }
  float rl = 0.f, tail = 0.f;
#pragma unroll 4
  for (int p = 0; p < b; ++p)           rl   += T_lo[p * DOUT + d];
#pragma unroll 4
  for (int p = b + 1; p < NCHUNK; ++p)  tail += T_hi[p * DOUT + d];
  float phl[CLEN], phh[CLEN];
  float ownHi = 0.f;
#pragma unroll
  for (int e = 0; e < CLEN; e += 4) {
    int4 p4 = *(const int4*)(perm + j0 + e);
    float4 wl4 = *(const float4*)(w_lo + j0 + e);
    float4 wh4 = *(const float4*)(w_hi + j0 + e);
    float h0 = h[(size_t)p4.x * DOUT + d];
    float h1 = h[(size_t)p4.y * DOUT + d];
    float h2 = h[(size_t)p4.z * DOUT + d];
    float h3 = h[(size_t)p4.w * DOUT + d];
    phl[e + 0] = wl4.x * h0; phl[e + 1] = wl4.y * h1;
    phl[e + 2] = wl4.z * h2; phl[e + 3] = wl4.w * h3;
    phh[e + 0] = wh4.x * h0; phh[e + 1] = wh4.y * h1;
    phh[e + 2] = wh4.z * h2; phh[e + 3] = wh4.w * h3;
    ownHi += phh[e + 0] + phh[e + 1] + phh[e + 2] + phh[e + 3];
  }
  float shb = tail + ownHi;
  float preh = 0.f;
#pragma unroll
  for (int e = 0; e < CLEN; ++e) {
    size_t j = (size_t)(j0 + e);
    PreLo[j * DOUT + d] = rl;
    SufHi[j * DOUT + d] = shb - preh;
    rl   += phl[e];
    preh += phh[e];
  }
  if (b == NCHUNK - 1) {
    PreLo[(size_t)NROW * DOUT + d] = rl;
    SufHi[(size_t)NROW * DOUT + d] = 0.f;
  }
}

__global__ __launch_bounds__(256) void finalize(const float* __restrict__ s2,
                                                const float* __restrict__ s1s,
                                                const float* __restrict__ miscf,
                                                const float* __restrict__ PreLo,
                                                const float* __restrict__ SufHi,
                                                const float* __restrict__ prelo_s,
                                                const float* __restrict__ sufhi_s,
                                                float* __restrict__ out) {
  const int wave = threadIdx.x >> 6, lane = threadIdx.x & 63;
  const int i = blockIdx.x * 4 + wave;
  const float c = s2[i];
  const float M1 = miscf[0];
  const float tval = -c;
  int lo = 0, hi = NROW;
  while (lo < hi) {
    int mid = (lo + hi) >> 1;
    if (s1s[mid] <= tval) lo = mid + 1; else hi = mid;
  }
  const int k = lo;
  const float u = c + M1;
  const float m = fmaxf(u, 0.2f * u);
  const float fh = __expf(u - m);
  const float fl = __expf(0.2f * u - m);
  const float den = fh * sufhi_s[k] + fl * prelo_s[k];
  const float inv = 1.f / den;
  float4 A = *(const float4*)(SufHi + (size_t)k * DOUT + (lane << 2));
  float4 B = *(const float4*)(PreLo + (size_t)k * DOUT + (lane << 2));
  float4 o;
  o.x = (fh * A.x + fl * B.x) * inv;
  o.y = (fh * A.y + fl * B.y) * inv;
  o.z = (fh * A.z + fl * B.z) * inv;
  o.w = (fh * A.w + fl * B.w) * inv;
  *(float4*)(out + (size_t)i * DOUT + (lane << 2)) = o;
}

extern "C" void kernel_launch(void* const* d_in, const int* in_sizes, int n_in,
                              void* d_out, int out_size, void* d_ws, size_t ws_size,
                              hipStream_t stream) {
  const float* x  = (const float*)d_in[0];
  const float* W  = (const float*)d_in[2];
  const float* a1 = (const float*)d_in[3];
  const float* a2 = (const float*)d_in[4];
  float* out = (float*)d_out;

  char* ws = (char*)d_ws;
  if (ws_size < WS_NEED) ws = (char*)d_in[1];  // fall back to unused adj buffer

  float*          h       = (float*)(ws + OFF_H);
  float*          s1      = (float*)(ws + OFF_S1);
  float*          s2      = (float*)(ws + OFF_S2);
  int*            rank    = (int*)  (ws + OFF_RANK);
  unsigned int*   miscu   = (unsigned int*)(ws + OFF_MISC);
  float*          miscf   = (float*)(ws + OFF_MISC) + 1;
  float*          s1s     = (float*)(ws + OFF_S1S);
  int*            perm    = (int*)  (ws + OFF_PERM);
  float*          w_hi    = (float*)(ws + OFF_WHI);
  float*          w_lo    = (float*)(ws + OFF_WLO);
  float*          prelo_s = (float*)(ws + OFF_PRELOS);
  float*          sufhi_s = (float*)(ws + OFF_SUFHIS);
  float*          cs_lo   = (float*)(ws + OFF_CSLO);
  float*          cs_hi   = (float*)(ws + OFF_CSHI);
  float*          T_lo    = (float*)(ws + OFF_TLO);
  float*          T_hi    = (float*)(ws + OFF_THI);
  float*          PreLo   = (float*)(ws + OFF_PRELO);
  float*          SufHi   = (float*)(ws + OFF_SUFHI);

  // zero s1,s2,rank,misc (contiguous) for the atomic accumulations
  hipMemsetAsync(s1, 0, MEMSET_LEN, stream);

  gemm_h_mfma<<<512, 256, 0, stream>>>(x, W, a1, a2, h, s1, s2);

  const float* s1c = s1;
  const float* s2c = s2;
  const float* hc  = h;
  void* args[] = {(void*)&s1c, (void*)&s2c, (void*)&rank, (void*)&miscu, (void*)&miscf,
                  (void*)&s1s, (void*)&perm, (void*)&w_hi, (void*)&w_lo,
                  (void*)&hc, (void*)&T_lo, (void*)&T_hi, (void*)&cs_lo, (void*)&cs_hi,
                  (void*)&PreLo, (void*)&SufHi, (void*)&prelo_s, (void*)&sufhi_s,
                  (void*)&out};
  hipError_t err = hipLaunchCooperativeKernel((void*)backend, dim3(512), dim3(256),
                                              args, 0, stream);
  if (err != hipSuccess) {  // fallback: original 5-kernel pipeline
    rank_count<<<dim3(NROW / 256, 8), 256, 0, stream>>>(s1, rank, miscu);
    scatter_w<<<NROW / 256, 256, 0, stream>>>(s1, rank, miscu, miscf, s1s, perm, w_hi, w_lo);
    chunk_totals<<<NCHUNK, 256, 0, stream>>>(h, perm, w_hi, w_lo, T_lo, T_hi, cs_lo, cs_hi);
    write_prefix<<<NCHUNK, 256, 0, stream>>>(h, perm, w_hi, w_lo, T_lo, T_hi, cs_lo, cs_hi,
                                             PreLo, SufHi, prelo_s, sufhi_s);
    finalize<<<NROW / 4, 256, 0, stream>>>(s2, s1s, miscf, PreLo, SufHi, prelo_s, sufhi_s, out);
  }
}

// Round 8
// 383.904 us; speedup vs baseline: 1.4855x; 1.4855x over previous
//
#include <hip/hip_runtime.h>

#define NROW 8192
#define DIN  512
#define DOUT 256
#define NCHUNK 256
#define CLEN 32   // NCHUNK*CLEN == NROW
#define NSLICE 8  // s1/s2 partial slices: 4 col-tiles x 2 wCol halves

// ---------------- workspace layout (bytes) ----------------
constexpr size_t OFF_H      = 0;                              // 8192*256*4
constexpr size_t OFF_S1P    = OFF_H + (size_t)NROW*DOUT*4;    // [NSLICE][NROW]
constexpr size_t OFF_S2P    = OFF_S1P + (size_t)NSLICE*NROW*4;
constexpr size_t OFF_RANKP  = OFF_S2P + (size_t)NSLICE*NROW*4; // [8][NROW] int
constexpr size_t OFF_BMAX   = OFF_RANKP + (size_t)8*NROW*4;    // [32] float
constexpr size_t OFF_MISC   = OFF_BMAX + 256;                  // [0]=M1 float
constexpr size_t OFF_S1S    = OFF_MISC + 256;
constexpr size_t OFF_PERM   = OFF_S1S + NROW*4;
constexpr size_t OFF_WHI    = OFF_PERM + NROW*4;
constexpr size_t OFF_WLO    = OFF_WHI + NROW*4;
constexpr size_t OFF_PRELOS = OFF_WLO + NROW*4;               // 8193 floats, padded
constexpr size_t OFF_SUFHIS = OFF_PRELOS + 33024;
constexpr size_t OFF_CSLO   = OFF_SUFHIS + 33024;             // [NCHUNK]
constexpr size_t OFF_CSHI   = OFF_CSLO + 1024;
constexpr size_t OFF_TLO    = OFF_CSHI + 1024;                // [NCHUNK][256]
constexpr size_t OFF_THI    = OFF_TLO + (size_t)NCHUNK*DOUT*4;
constexpr size_t OFF_PRELO  = OFF_THI + (size_t)NCHUNK*DOUT*4;  // [8193][256]
constexpr size_t OFF_SUFHI  = OFF_PRELO + (size_t)(NROW+1)*DOUT*4;
constexpr size_t WS_NEED    = OFF_SUFHI + (size_t)(NROW+1)*DOUT*4;

typedef float f32x4 __attribute__((ext_vector_type(4)));
typedef short s16x8 __attribute__((ext_vector_type(8)));
typedef unsigned int u32x4 __attribute__((ext_vector_type(4)));

// fp32 x8 -> bf16 hi/lo TRUNCATING split, 3 VALU ops/element (v_perm packs
// two truncations per instruction). Error on h ~2e-5, two orders below the
// observed absmax floor.
__device__ __forceinline__ void cvt8_pair(const float4 u, const float4 v,
                                          s16x8& hi, s16x8& lo) {
  float f[8] = {u.x, u.y, u.z, u.w, v.x, v.y, v.z, v.w};
  u32x4 hp, lp;
#pragma unroll
  for (int p = 0; p < 4; ++p) {
    const float f0 = f[2 * p], f1 = f[2 * p + 1];
    const unsigned b0 = __float_as_uint(f0);
    const unsigned b1 = __float_as_uint(f1);
    hp[p] = __builtin_amdgcn_perm(b1, b0, 0x07060302u);  // [f0.hi16, f1.hi16]
    const float r0 = f0 - __uint_as_float(b0 & 0xffff0000u);
    const float r1 = f1 - __uint_as_float(b1 & 0xffff0000u);
    lp[p] = __builtin_amdgcn_perm(__float_as_uint(r1), __float_as_uint(r0), 0x07060302u);
  }
  hi = __builtin_bit_cast(s16x8, hp);
  lo = __builtin_bit_cast(s16x8, lp);
}

// ------- kernel 1: h = x @ W^T via split-bf16 MFMA, s1/s2 partial slices ---
// Round-6 structure (64x64 tile, BK=64, 512 blocks = 2/CU, XCD swizzle,
// in-kernel truncating conversion). Epilogue change: instead of atomicAdd
// into s1/s2 (which required a memset dispatch), each (col-tile, wCol) slice
// WRITES its 32-col partial to s1p/s2p[slice][row] — disjoint writers,
// no atomics, no zero-init. Consumers sum the 8 slices (L2-hot, 256 KB).
__global__ __launch_bounds__(256) void gemm_h_mfma(const float* __restrict__ x,
                                                   const float* __restrict__ W,
                                                   const float* __restrict__ a1,
                                                   const float* __restrict__ a2,
                                                   float* __restrict__ h,
                                                   float* __restrict__ s1p,
                                                   float* __restrict__ s2p) {
  __shared__ unsigned short AsH[64][72], AsL[64][72], BsH[64][72], BsL[64][72];
  const int tid = threadIdx.x;
  const int bid = blockIdx.x;
  const int swz = (bid & 7) * 64 + (bid >> 3);
  const int rowBase = (swz >> 2) * 64;
  const int colBase = (swz & 3) * 64;
  const int wid = tid >> 6, lane = tid & 63;
  const int wRow = wid >> 1, wCol = wid & 1;
  const int lhi = lane >> 4, llo = lane & 15;

  f32x4 acc[2][2];
#pragma unroll
  for (int m = 0; m < 2; ++m)
#pragma unroll
    for (int n = 0; n < 2; ++n) acc[m][n] = (f32x4)(0.f);

  const int tr = tid >> 2;
  const int tq = tid & 3;
  const float* px = x + (size_t)(rowBase + tr) * DIN + tq * 16;
  const float* pw = W + (size_t)(colBase + tr) * DIN + tq * 16;

  s16x8 cAh[2], cAl[2], cBh[2], cBl[2];
  {
    float4 a0 = *(const float4*)(px + 0),  a1v = *(const float4*)(px + 4);
    float4 a2v = *(const float4*)(px + 8), a3 = *(const float4*)(px + 12);
    float4 b0 = *(const float4*)(pw + 0),  b1 = *(const float4*)(pw + 4);
    float4 b2 = *(const float4*)(pw + 8),  b3 = *(const float4*)(pw + 12);
    cvt8_pair(a0, a1v, cAh[0], cAl[0]);
    cvt8_pair(a2v, a3, cAh[1], cAl[1]);
    cvt8_pair(b0, b1, cBh[0], cBl[0]);
    cvt8_pair(b2, b3, cBh[1], cBl[1]);
  }

  for (int k0 = 0; k0 < DIN; k0 += 64) {
    __syncthreads();
    *(s16x8*)&AsH[tr][tq * 16 + 0] = cAh[0];
    *(s16x8*)&AsH[tr][tq * 16 + 8] = cAh[1];
    *(s16x8*)&AsL[tr][tq * 16 + 0] = cAl[0];
    *(s16x8*)&AsL[tr][tq * 16 + 8] = cAl[1];
    *(s16x8*)&BsH[tr][tq * 16 + 0] = cBh[0];
    *(s16x8*)&BsH[tr][tq * 16 + 8] = cBh[1];
    *(s16x8*)&BsL[tr][tq * 16 + 0] = cBl[0];
    *(s16x8*)&BsL[tr][tq * 16 + 8] = cBl[1];
    __syncthreads();
    const bool more = (k0 + 64 < DIN);
    float4 a0, a1v, a2v, a3, b0, b1, b2, b3;
    if (more) {
      a0 = *(const float4*)(px + k0 + 64 + 0);  a1v = *(const float4*)(px + k0 + 64 + 4);
      a2v = *(const float4*)(px + k0 + 64 + 8); a3 = *(const float4*)(px + k0 + 64 + 12);
      b0 = *(const float4*)(pw + k0 + 64 + 0);  b1 = *(const float4*)(pw + k0 + 64 + 4);
      b2 = *(const float4*)(pw + k0 + 64 + 8);  b3 = *(const float4*)(pw + k0 + 64 + 12);
    }
#pragma unroll
    for (int kk = 0; kk < 64; kk += 32) {
      s16x8 afh[2], afl[2], bfh[2], bfl[2];
#pragma unroll
      for (int m = 0; m < 2; ++m) {
        afh[m] = *(const s16x8*)&AsH[wRow * 32 + m * 16 + llo][kk + lhi * 8];
        afl[m] = *(const s16x8*)&AsL[wRow * 32 + m * 16 + llo][kk + lhi * 8];
      }
#pragma unroll
      for (int n = 0; n < 2; ++n) {
        bfh[n] = *(const s16x8*)&BsH[wCol * 32 + n * 16 + llo][kk + lhi * 8];
        bfl[n] = *(const s16x8*)&BsL[wCol * 32 + n * 16 + llo][kk + lhi * 8];
      }
#pragma unroll
      for (int m = 0; m < 2; ++m)
#pragma unroll
        for (int n = 0; n < 2; ++n) {
          acc[m][n] = __builtin_amdgcn_mfma_f32_16x16x32_bf16(afh[m], bfh[n], acc[m][n], 0, 0, 0);
          acc[m][n] = __builtin_amdgcn_mfma_f32_16x16x32_bf16(afl[m], bfh[n], acc[m][n], 0, 0, 0);
          acc[m][n] = __builtin_amdgcn_mfma_f32_16x16x32_bf16(afh[m], bfl[n], acc[m][n], 0, 0, 0);
        }
    }
    if (more) {
      cvt8_pair(a0, a1v, cAh[0], cAl[0]);
      cvt8_pair(a2v, a3, cAh[1], cAl[1]);
      cvt8_pair(b0, b1, cBh[0], cBl[0]);
      cvt8_pair(b2, b3, cBh[1], cBl[1]);
    }
  }
  // C/D layout (m89-verified): col = lane&15, row = (lane>>4)*4 + reg
  float a1c[2], a2c[2];
#pragma unroll
  for (int n = 0; n < 2; ++n) {
    const int col = colBase + wCol * 32 + n * 16 + llo;
    a1c[n] = a1[col];
    a2c[n] = a2[col];
  }
  const int slice = (swz & 3) * 2 + wCol;  // 0..7, unique (colTile, half)
#pragma unroll
  for (int m = 0; m < 2; ++m) {
    float p1[4] = {0.f, 0.f, 0.f, 0.f}, p2[4] = {0.f, 0.f, 0.f, 0.f};
#pragma unroll
    for (int n = 0; n < 2; ++n) {
      const int col = colBase + wCol * 32 + n * 16 + llo;
#pragma unroll
      for (int j = 0; j < 4; ++j) {
        const int row = rowBase + wRow * 32 + m * 16 + lhi * 4 + j;
        h[(size_t)row * DOUT + col] = acc[m][n][j];
        p1[j] = fmaf(acc[m][n][j], a1c[n], p1[j]);
        p2[j] = fmaf(acc[m][n][j], a2c[n], p2[j]);
      }
    }
#pragma unroll
    for (int j = 0; j < 4; ++j) {
#pragma unroll
      for (int msk = 1; msk < 16; msk <<= 1) {
        p1[j] += __shfl_xor(p1[j], msk);
        p2[j] += __shfl_xor(p2[j], msk);
      }
    }
    if (llo == 0) {  // lanes 0,16,32,48: lhi = 0..3
#pragma unroll
      for (int j = 0; j < 4; ++j) {
        const int row = rowBase + wRow * 32 + m * 16 + lhi * 4 + j;
        s1p[slice * NROW + row] = p1[j];
        s2p[slice * NROW + row] = p2[j];
      }
    }
  }
}

// ------- kernel 2: rank partials (direct write) + per-ib block max ---------
__global__ __launch_bounds__(256) void rank_count(const float* __restrict__ s1p,
                                                  int* __restrict__ rankp,
                                                  float* __restrict__ bmax) {
  __shared__ float sj[1024];
  __shared__ float wm[4];
  const int t = threadIdx.x;
  const int ib = blockIdx.x, jc = blockIdx.y;
  const int j0 = jc * 1024;
  // sj[q] = s1[j0+q] = sum of 8 slice partials (fixed order -> deterministic)
  {
    float4 a = (float4){0.f, 0.f, 0.f, 0.f};
#pragma unroll
    for (int p = 0; p < NSLICE; ++p) {
      float4 v = *(const float4*)(s1p + (size_t)p * NROW + j0 + (t << 2));
      a.x += v.x; a.y += v.y; a.z += v.z; a.w += v.w;
    }
    *(float4*)&sj[t << 2] = a;
  }
  const int i = ib * 256 + t;
  float v = 0.f;
#pragma unroll
  for (int p = 0; p < NSLICE; ++p) v += s1p[(size_t)p * NROW + i];
  __syncthreads();
  int cnt = 0;
#pragma unroll 4
  for (int q = 0; q < 256; ++q) {
    float4 sv = *(const float4*)&sj[q << 2];
    int jg = j0 + (q << 2);
    cnt += (int)(sv.x < v) + (int)((sv.x == v) & (jg + 0 < i));
    cnt += (int)(sv.y < v) + (int)((sv.y == v) & (jg + 1 < i));
    cnt += (int)(sv.z < v) + (int)((sv.z == v) & (jg + 2 < i));
    cnt += (int)(sv.w < v) + (int)((sv.w == v) & (jg + 3 < i));
  }
  rankp[jc * NROW + i] = cnt;   // direct write, no atomics
  if (jc == 0) {                // per-ib max of s1 (no atomic: bmax[ib])
    float m = v;
#pragma unroll
    for (int off = 32; off > 0; off >>= 1) m = fmaxf(m, __shfl_down(m, off));
    if ((t & 63) == 0) wm[t >> 6] = m;
    __syncthreads();
    if (t == 0) bmax[ib] = fmaxf(fmaxf(wm[0], wm[1]), fmaxf(wm[2], wm[3]));
  }
}

// ------- kernel 3: scatter into sorted order + exp weights -----------------
__global__ __launch_bounds__(256) void scatter_w(const float* __restrict__ s1p,
                                                 const int* __restrict__ rankp,
                                                 const float* __restrict__ bmax,
                                                 float* __restrict__ miscf,
                                                 float* __restrict__ s1s,
                                                 int* __restrict__ perm,
                                                 float* __restrict__ w_hi,
                                                 float* __restrict__ w_lo) {
  const int i = blockIdx.x * 256 + threadIdx.x;
  float M1 = bmax[0];
#pragma unroll
  for (int p = 1; p < 32; ++p) M1 = fmaxf(M1, bmax[p]);  // uniform -> scalar
  float v = 0.f;
#pragma unroll
  for (int p = 0; p < NSLICE; ++p) v += s1p[(size_t)p * NROW + i];  // same order as rank
  int r = 0;
#pragma unroll
  for (int p = 0; p < 8; ++p) r += rankp[p * NROW + i];
  s1s[r] = v;
  perm[r] = i;
  w_hi[r] = __expf(v - M1);
  w_lo[r] = __expf(0.2f * (v - M1));
  if (i == 0) miscf[0] = M1;
}

// ------- kernel 4: per-chunk weighted totals + scalar chunk sums -----------
__global__ __launch_bounds__(256) void chunk_totals(const float* __restrict__ h,
                                                    const int* __restrict__ perm,
                                                    const float* __restrict__ w_hi,
                                                    const float* __restrict__ w_lo,
                                                    float* __restrict__ T_lo,
                                                    float* __restrict__ T_hi,
                                                    float* __restrict__ cs_lo,
                                                    float* __restrict__ cs_hi) {
  const int d = threadIdx.x, b = blockIdx.x;
  const int j0 = b * CLEN;
  float tlo = 0.f, thi = 0.f;
#pragma unroll
  for (int e = 0; e < CLEN; e += 4) {
    int4 p4 = *(const int4*)(perm + j0 + e);
    float4 wl4 = *(const float4*)(w_lo + j0 + e);
    float4 wh4 = *(const float4*)(w_hi + j0 + e);
    float h0 = h[(size_t)p4.x * DOUT + d];
    float h1 = h[(size_t)p4.y * DOUT + d];
    float h2 = h[(size_t)p4.z * DOUT + d];
    float h3 = h[(size_t)p4.w * DOUT + d];
    tlo += wl4.x * h0 + wl4.y * h1 + wl4.z * h2 + wl4.w * h3;
    thi += wh4.x * h0 + wh4.y * h1 + wh4.z * h2 + wh4.w * h3;
  }
  T_lo[b * DOUT + d] = tlo;
  T_hi[b * DOUT + d] = thi;
  if (d < 64) {
    float wl = (d < 32) ? w_lo[j0 + d] : 0.f;
    float wh = (d < 32) ? w_hi[j0 + d] : 0.f;
#pragma unroll
    for (int off = 32; off > 0; off >>= 1) {
      wl += __shfl_down(wl, off);
      wh += __shfl_down(wh, off);
    }
    if (d == 0) { cs_lo[b] = wl; cs_hi[b] = wh; }
  }
}

// ------- kernel 5: chunk-offset sums + materialize PreLo/SufHi + scalars ---
__global__ __launch_bounds__(256) void write_prefix(const float* __restrict__ h,
                                                    const int* __restrict__ perm,
                                                    const float* __restrict__ w_hi,
                                                    const float* __restrict__ w_lo,
                                                    const float* __restrict__ T_lo,
                                                    const float* __restrict__ T_hi,
                                                    const float* __restrict__ cs_lo,
                                                    const float* __restrict__ cs_hi,
                                                    float* __restrict__ PreLo,
                                                    float* __restrict__ SufHi,
                                                    float* __restrict__ prelo_s,
                                                    float* __restrict__ sufhi_s) {
  const int d = threadIdx.x, b = blockIdx.x;
  const int j0 = b * CLEN;
  if (d < 64) {
    float accp = 0.f, acct = 0.f;
    for (int p = d; p < NCHUNK; p += 64) {
      float cl = cs_lo[p], ch = cs_hi[p];
      accp += (p < b) ? cl : 0.f;
      acct += (p > b) ? ch : 0.f;
    }
#pragma unroll
    for (int off = 32; off > 0; off >>= 1) {
      accp += __shfl_down(accp, off);
      acct += __shfl_down(acct, off);
    }
    float pres  = __shfl(accp, 0);
    float tails = __shfl(acct, 0);
    float wl = (d < 32) ? w_lo[j0 + d] : 0.f;
    float wh = (d < 32) ? w_hi[j0 + d] : 0.f;
    float pl = wl, ph = wh;
#pragma unroll
    for (int off = 1; off < 32; off <<= 1) {
      float a = __shfl_up(pl, off);
      float c = __shfl_up(ph, off);
      if (d >= off) { pl += a; ph += c; }
    }
    float chunk_hi_tot = __shfl(ph, 31);
    if (d < 32) {
      prelo_s[j0 + d] = pres + (pl - wl);
      sufhi_s[j0 + d] = tails + (chunk_hi_tot - (ph - wh));
    }
    if (b == NCHUNK - 1 && d == 31) {
      prelo_s[NROW] = pres + pl;
      sufhi_s[NROW] = 0.f;
    }
  }
  float rl = 0.f, tail = 0.f;
#pragma unroll 4
  for (int p = 0; p < b; ++p)           rl   += T_lo[p * DOUT + d];
#pragma unroll 4
  for (int p = b + 1; p < NCHUNK; ++p)  tail += T_hi[p * DOUT + d];
  float phl[CLEN], phh[CLEN];
  float ownHi = 0.f;
#pragma unroll
  for (int e = 0; e < CLEN; e += 4) {
    int4 p4 = *(const int4*)(perm + j0 + e);
    float4 wl4 = *(const float4*)(w_lo + j0 + e);
    float4 wh4 = *(const float4*)(w_hi + j0 + e);
    float h0 = h[(size_t)p4.x * DOUT + d];
    float h1 = h[(size_t)p4.y * DOUT + d];
    float h2 = h[(size_t)p4.z * DOUT + d];
    float h3 = h[(size_t)p4.w * DOUT + d];
    phl[e + 0] = wl4.x * h0; phl[e + 1] = wl4.y * h1;
    phl[e + 2] = wl4.z * h2; phl[e + 3] = wl4.w * h3;
    phh[e + 0] = wh4.x * h0; phh[e + 1] = wh4.y * h1;
    phh[e + 2] = wh4.z * h2; phh[e + 3] = wh4.w * h3;
    ownHi += phh[e + 0] + phh[e + 1] + phh[e + 2] + phh[e + 3];
  }
  float shb = tail + ownHi;
  float preh = 0.f;
#pragma unroll
  for (int e = 0; e < CLEN; ++e) {
    size_t j = (size_t)(j0 + e);
    PreLo[j * DOUT + d] = rl;
    SufHi[j * DOUT + d] = shb - preh;
    rl   += phl[e];
    preh += phh[e];
  }
  if (b == NCHUNK - 1) {
    PreLo[(size_t)NROW * DOUT + d] = rl;
    SufHi[(size_t)NROW * DOUT + d] = 0.f;
  }
}

// ---------------- kernel 6: per-row combine -------------------------------
__global__ __launch_bounds__(256) void finalize(const float* __restrict__ s2p,
                                                const float* __restrict__ s1s,
                                                const float* __restrict__ miscf,
                                                const float* __restrict__ PreLo,
                                                const float* __restrict__ SufHi,
                                                const float* __restrict__ prelo_s,
                                                const float* __restrict__ sufhi_s,
                                                float* __restrict__ out) {
  const int wave = threadIdx.x >> 6, lane = threadIdx.x & 63;
  const int i = blockIdx.x * 4 + wave;
  float c = 0.f;
#pragma unroll
  for (int p = 0; p < NSLICE; ++p) c += s2p[(size_t)p * NROW + i];
  const float M1 = miscf[0];
  const float tval = -c;
  int lo = 0, hi = NROW;
  while (lo < hi) {
    int mid = (lo + hi) >> 1;
    if (s1s[mid] <= tval) lo = mid + 1; else hi = mid;
  }
  const int k = lo;
  const float u = c + M1;
  const float m = fmaxf(u, 0.2f * u);
  const float fh = __expf(u - m);
  const float fl = __expf(0.2f * u - m);
  const float den = fh * sufhi_s[k] + fl * prelo_s[k];
  const float inv = 1.f / den;
  float4 A = *(const float4*)(SufHi + (size_t)k * DOUT + (lane << 2));
  float4 B = *(const float4*)(PreLo + (size_t)k * DOUT + (lane << 2));
  float4 o;
  o.x = (fh * A.x + fl * B.x) * inv;
  o.y = (fh * A.y + fl * B.y) * inv;
  o.z = (fh * A.z + fl * B.z) * inv;
  o.w = (fh * A.w + fl * B.w) * inv;
  *(float4*)(out + (size_t)i * DOUT + (lane << 2)) = o;
}

extern "C" void kernel_launch(void* const* d_in, const int* in_sizes, int n_in,
                              void* d_out, int out_size, void* d_ws, size_t ws_size,
                              hipStream_t stream) {
  const float* x  = (const float*)d_in[0];
  const float* W  = (const float*)d_in[2];
  const float* a1 = (const float*)d_in[3];
  const float* a2 = (const float*)d_in[4];
  float* out = (float*)d_out;

  char* ws = (char*)d_ws;
  if (ws_size < WS_NEED) ws = (char*)d_in[1];  // fall back to unused adj buffer

  float* h       = (float*)(ws + OFF_H);
  float* s1p     = (float*)(ws + OFF_S1P);
  float* s2p     = (float*)(ws + OFF_S2P);
  int*   rankp   = (int*)  (ws + OFF_RANKP);
  float* bmax    = (float*)(ws + OFF_BMAX);
  float* miscf   = (float*)(ws + OFF_MISC);
  float* s1s     = (float*)(ws + OFF_S1S);
  int*   perm    = (int*)  (ws + OFF_PERM);
  float* w_hi    = (float*)(ws + OFF_WHI);
  float* w_lo    = (float*)(ws + OFF_WLO);
  float* prelo_s = (float*)(ws + OFF_PRELOS);
  float* sufhi_s = (float*)(ws + OFF_SUFHIS);
  float* cs_lo   = (float*)(ws + OFF_CSLO);
  float* cs_hi   = (float*)(ws + OFF_CSHI);
  float* T_lo    = (float*)(ws + OFF_TLO);
  float* T_hi    = (float*)(ws + OFF_THI);
  float* PreLo   = (float*)(ws + OFF_PRELO);
  float* SufHi   = (float*)(ws + OFF_SUFHI);

  // no memset: every buffer is fully written before it is read
  gemm_h_mfma<<<512, 256, 0, stream>>>(x, W, a1, a2, h, s1p, s2p);
  rank_count<<<dim3(NROW / 256, 8), 256, 0, stream>>>(s1p, rankp, bmax);
  scatter_w<<<NROW / 256, 256, 0, stream>>>(s1p, rankp, bmax, miscf, s1s, perm, w_hi, w_lo);
  chunk_totals<<<NCHUNK, 256, 0, stream>>>(h, perm, w_hi, w_lo, T_lo, T_hi, cs_lo, cs_hi);
  write_prefix<<<NCHUNK, 256, 0, stream>>>(h, perm, w_hi, w_lo, T_lo, T_hi, cs_lo, cs_hi,
                                           PreLo, SufHi, prelo_s, sufhi_s);
  finalize<<<NROW / 4, 256, 0, stream>>>(s2p, s1s, miscf, PreLo, SufHi, prelo_s, sufhi_s, out);
}